// Round 9
// baseline (179.107 us; speedup 1.0000x reference)
//
#include <hip/hip_runtime.h>
#include <hip/hip_fp16.h>

// GCN 2-layer: out = A(relu(A x W1 + b1) W2) + b2, A = sym-normalized adj + self-loops.
// R9: k_l1w was still latency-bound (65us, VALUBusy 42%): 16 edges in flight, chain
// depth 6-8. v3 uses 2 lanes/edge with 16B half8 gathers -> 32 edges in flight, depth 3
// (rowptr -> 32 parallel col -> 32 parallel gathers -> shuffle fold). k_l2w: 32 lanes/row.

#define B 256
#define NB_MAX 1024
#define BDIV 128          // nodes per bucket (pow2)
#define BSHIFT 7
#define CHUNK 8192        // edges per partition block

// ---------------- partition: per-block LDS histogram over buckets ----------------
__global__ __launch_bounds__(256) void k_phist(const int* __restrict__ dst,
                                               int* __restrict__ hists,
                                               int E, int NB, int NBLK) {
    __shared__ int h[NB_MAX];
    int tid = threadIdx.x, blk = blockIdx.x;
    for (int b = tid; b < NB; b += 256) h[b] = 0;
    __syncthreads();
    int start = blk * CHUNK;
    int end = min(start + CHUNK, E);
    for (int e = start + tid; e < end; e += 256)
        atomicAdd(&h[((unsigned)dst[e]) >> BSHIFT], 1);
    __syncthreads();
    for (int b = tid; b < NB; b += 256) hists[b * NBLK + blk] = h[b];
}

// per-bucket exclusive scan over NBLK block-counts (NBLK <= 512)
__global__ __launch_bounds__(512) void k_pscan1(int* __restrict__ hists,
                                                int* __restrict__ totals, int NBLK) {
    __shared__ int s[512];
    int b = blockIdx.x, tid = threadIdx.x;
    int v = (tid < NBLK) ? hists[b * NBLK + tid] : 0;
    s[tid] = v;
    __syncthreads();
    for (int off = 1; off < 512; off <<= 1) {
        int u = (tid >= off) ? s[tid - off] : 0;
        __syncthreads();
        s[tid] += u;
        __syncthreads();
    }
    if (tid < NBLK) hists[b * NBLK + tid] = s[tid] - v;  // exclusive within bucket
    if (tid == 511) totals[b] = s[511];
}

// scan bucket totals -> bucket bases (NB <= 1024); base[NB]=E; rowptr[n]=E
__global__ __launch_bounds__(1024) void k_pscan2(const int* __restrict__ totals,
                                                 int* __restrict__ base, int NB,
                                                 int* __restrict__ rowptr, int n, int E) {
    __shared__ int s[1024];
    int tid = threadIdx.x;
    int v = (tid < NB) ? totals[tid] : 0;
    s[tid] = v;
    __syncthreads();
    for (int off = 1; off < 1024; off <<= 1) {
        int u = (tid >= off) ? s[tid - off] : 0;
        __syncthreads();
        s[tid] += u;
        __syncthreads();
    }
    if (tid < NB) base[tid] = s[tid] - v;
    if (tid == 1023) { base[NB] = s[1023]; rowptr[n] = E; }
}

// move edges into bucket regions, LDS-staged for coalesced writes.
__global__ __launch_bounds__(256) void k_move(const int* __restrict__ src,
                                              const int* __restrict__ dst,
                                              const int* __restrict__ hists,
                                              const int* __restrict__ base,
                                              unsigned* __restrict__ packed,
                                              int E, int NB, int NBLK) {
    __shared__ unsigned stage[CHUNK];            // 32 KB
    __shared__ unsigned short stage_b[CHUNK];    // 16 KB
    __shared__ int lh[NB_MAX];
    __shared__ int lexc[NB_MAX];
    __shared__ int gb[NB_MAX];
    __shared__ int part[256];
    int tid = threadIdx.x, blk = blockIdx.x;
    int start = blk * CHUNK;
    int end = min(start + CHUNK, E);
    for (int b = tid; b < NB; b += 256) lh[b] = 0;
    __syncthreads();
    for (int e = start + tid; e < end; e += 256)
        atomicAdd(&lh[((unsigned)dst[e]) >> BSHIFT], 1);
    __syncthreads();
    int t4 = tid * 4;
    int a0 = 0, a1 = 0, a2 = 0, a3 = 0;
    if (t4 + 0 < NB) a0 = lh[t4 + 0];
    if (t4 + 1 < NB) a1 = lh[t4 + 1];
    if (t4 + 2 < NB) a2 = lh[t4 + 2];
    if (t4 + 3 < NB) a3 = lh[t4 + 3];
    int sum = a0 + a1 + a2 + a3;
    part[tid] = sum;
    __syncthreads();
    for (int off = 1; off < 256; off <<= 1) {
        int u = (tid >= off) ? part[tid - off] : 0;
        __syncthreads();
        part[tid] += u;
        __syncthreads();
    }
    int run = part[tid] - sum;
    if (t4 + 0 < NB) { lexc[t4 + 0] = run; run += a0; }
    if (t4 + 1 < NB) { lexc[t4 + 1] = run; run += a1; }
    if (t4 + 2 < NB) { lexc[t4 + 2] = run; run += a2; }
    if (t4 + 3 < NB) { lexc[t4 + 3] = run; run += a3; }
    __syncthreads();
    for (int b = tid; b < NB; b += 256) {
        lh[b] = lexc[b];
        gb[b] = base[b] + hists[b * NBLK + blk] - lexc[b];
    }
    __syncthreads();
    for (int e = start + tid; e < end; e += 256) {
        unsigned d = (unsigned)dst[e];
        int b = d >> BSHIFT;
        int r = atomicAdd(&lh[b], 1);
        stage[r] = (unsigned)src[e] | ((d & (BDIV - 1u)) << 20);
        stage_b[r] = (unsigned short)b;
    }
    __syncthreads();
    int cnt = end - start;
    for (int i = tid; i < cnt; i += 256)
        packed[gb[stage_b[i]] + i] = stage[i];
}

// per-bucket: LDS hist over 128 local nodes -> scan -> rowptr/dinv + place col
__global__ __launch_bounds__(256) void k_bucket_csr(const unsigned* __restrict__ packed,
                                                    const int* __restrict__ base,
                                                    int* __restrict__ rowptr,
                                                    float* __restrict__ dinv,
                                                    int* __restrict__ col, int n) {
    __shared__ int lcnt[BDIV];
    __shared__ int lexc[BDIV];
    int b = blockIdx.x, tid = threadIdx.x;
    if (tid < BDIV) lcnt[tid] = 0;
    __syncthreads();
    int s0 = base[b], s1 = base[b + 1];
    for (int i = s0 + tid; i < s1; i += 256)
        atomicAdd(&lcnt[packed[i] >> 20], 1);
    __syncthreads();
    int v = (tid < BDIV) ? lcnt[tid] : 0;
    if (tid < BDIV) lexc[tid] = v;
    __syncthreads();
    for (int off = 1; off < BDIV; off <<= 1) {
        int u = (tid < BDIV && tid >= off) ? lexc[tid - off] : 0;
        __syncthreads();
        if (tid < BDIV) lexc[tid] += u;
        __syncthreads();
    }
    if (tid < BDIV) {
        lexc[tid] -= v;  // exclusive
        int node = b * BDIV + tid;
        if (node < n) {
            rowptr[node] = s0 + lexc[tid];
            dinv[node] = rsqrtf((float)(v + 1));  // +1 self-loop
        }
        lcnt[tid] = 0;  // reuse as fill cursor
    }
    __syncthreads();
    for (int i = s0 + tid; i < s1; i += 256) {
        unsigned u = packed[i];
        int l = (int)(u >> 20);
        int pos = s0 + lexc[l] + atomicAdd(&lcnt[l], 1);
        col[pos] = (int)(u & 0xFFFFFu);
    }
}

// ---------------- x16 = fp16(x * dinv): L2-resident gather operand ----------------
__global__ void k_prep(const float* __restrict__ x, const float* __restrict__ dinv,
                       __half2* __restrict__ x16, int n8) {
    int g = blockIdx.x * blockDim.x + threadIdx.x;  // one half2 (2 feats)
    if (g >= n8) return;
    float d = dinv[g >> 3];
    float2 v = ((const float2*)x)[g];
    x16[g] = __float22half2_rn(make_float2(v.x * d, v.y * d));
}

// ---------------- layer 1: 2 lanes/edge, 32 edges in flight, fused MLP ----------
// lane = (h = lane&1 feat-half, eg = lane>>1 in [0,32)). Each lane gathers 16B
// (half8 = 8 feats). Avg-degree rows finish gather in ONE parallel round-trip.
// Fold over eg: shfl_xor offsets 2..32 on 8 f32 accumulators.
__global__ __launch_bounds__(256) void k_l1w(const __half2* __restrict__ x16,
                                             const int* __restrict__ rowptr,
                                             const int* __restrict__ col,
                                             const float* __restrict__ dinv,
                                             const float* __restrict__ W1,
                                             const float* __restrict__ b1,
                                             const float* __restrict__ W2,
                                             float* __restrict__ t, int n) {
    __shared__ float sW1[512], sW2[64], sb1[32];
    int tid = threadIdx.x;
    for (int k = tid; k < 512; k += 256) sW1[k] = W1[k];
    if (tid < 64) sW2[tid] = W2[tid];
    if (tid < 32) sb1[tid] = b1[tid];
    __syncthreads();
    int lane = tid & 63;
    int r = blockIdx.x * 4 + (tid >> 6);
    if (r >= n) return;
    int h = lane & 1, eg = lane >> 1;
    float dr = dinv[r];
    int beg = rowptr[r], fin = rowptr[r + 1];
    float s[8];
#pragma unroll
    for (int k = 0; k < 8; ++k) s[k] = 0.f;
    if (eg == 0) {  // self-loop: x16[r] already scaled by dinv_r; *dr later
        float4 raw = *(const float4*)(x16 + (size_t)r * 8 + h * 4);
        const __half2* hp = (const __half2*)&raw;
#pragma unroll
        for (int q = 0; q < 4; ++q) {
            float2 f = __half22float2(hp[q]);
            s[2 * q] += f.x; s[2 * q + 1] += f.y;
        }
    }
    for (int j = beg + eg; j < fin; j += 32) {
        int sc = col[j];
        float4 raw = *(const float4*)(x16 + (size_t)sc * 8 + h * 4);
        const __half2* hp = (const __half2*)&raw;
#pragma unroll
        for (int q = 0; q < 4; ++q) {
            float2 f = __half22float2(hp[q]);
            s[2 * q] += f.x; s[2 * q + 1] += f.y;
        }
    }
    // fold across eg (lane bits 1..5)
#pragma unroll
    for (int off = 2; off <= 32; off <<= 1) {
#pragma unroll
        for (int k = 0; k < 8; ++k) s[k] += __shfl_xor(s[k], off);
    }
#pragma unroll
    for (int k = 0; k < 8; ++k) s[k] *= dr;
    // lane0 (h=0): feats 0-7; lane1 (h=1): feats 8-15
    int j32 = lane & 31;
    float hv = sb1[j32];
#pragma unroll
    for (int k = 0; k < 8; ++k) {
        float a0 = __shfl(s[k], 0);
        float a1 = __shfl(s[k], 1);
        hv = fmaf(a0, sW1[k * 32 + j32], hv);
        hv = fmaf(a1, sW1[(k + 8) * 32 + j32], hv);
    }
    hv = fmaxf(hv, 0.f);
    float p = hv * sW2[j32 * 2 + (lane >> 5)];  // lanes<32 -> t0, lanes>=32 -> t1
#pragma unroll
    for (int off = 1; off <= 16; off <<= 1) p += __shfl_xor(p, off);
    if ((lane & 31) == 0) t[(size_t)r * 2 + (lane >> 5)] = p * dr;  // pre-scaled
}

// ---------------- layer 2: 32 lanes per row (2 rows/wave), 1 edge/lane ----------
__global__ __launch_bounds__(256) void k_l2w(const int* __restrict__ rowptr,
                                             const int* __restrict__ col,
                                             const float* __restrict__ dinv,
                                             const float* __restrict__ ts,
                                             const float* __restrict__ b2,
                                             float* __restrict__ out, int n) {
    int tid = threadIdx.x;
    int lane = tid & 63;
    int q = lane & 31;
    int i = blockIdx.x * 8 + ((tid >> 6) << 1) + (lane >> 5);
    if (i >= n) return;
    float di = dinv[i];
    int beg = rowptr[i], fin = rowptr[i + 1];
    float a0 = 0.f, a1 = 0.f;
    if (q == 0) {  // self: ts[i] = t*dinv_i; *di at end -> t*dinv_i^2
        float2 tv = *(const float2*)(ts + (size_t)i * 2);
        a0 = tv.x; a1 = tv.y;
    }
    for (int j = beg + q; j < fin; j += 32) {
        int sc = col[j];
        float2 tv = *(const float2*)(ts + (size_t)sc * 2);
        a0 += tv.x; a1 += tv.y;
    }
#pragma unroll
    for (int off = 1; off <= 16; off <<= 1) {
        a0 += __shfl_xor(a0, off);
        a1 += __shfl_xor(a1, off);
    }
    if (q == 0) {
        out[(size_t)i * 2 + 0] = fmaf(a0, di, b2[0]);
        out[(size_t)i * 2 + 1] = fmaf(a1, di, b2[1]);
    }
}

// ---------------- R3 CSR fallback kernels (global-atomic build) ----------------

__global__ void k_zero(int* __restrict__ cnt, int n) {
    int i = blockIdx.x * blockDim.x + threadIdx.x;
    if (i < n) cnt[i] = 0;
}
__global__ void k_hist_rank(const int* __restrict__ dst, int* __restrict__ cnt,
                            int* __restrict__ rank, int E) {
    int e = blockIdx.x * blockDim.x + threadIdx.x;
    if (e < E) rank[e] = atomicAdd(&cnt[dst[e]], 1);
}
__global__ __launch_bounds__(256) void k_blocksum(const int* __restrict__ cnt,
                                                  int* __restrict__ bsum, int n) {
    __shared__ int s[256];
    int tid = threadIdx.x;
    int bse = blockIdx.x * 1024 + tid * 4;
    int sum = 0;
#pragma unroll
    for (int q = 0; q < 4; ++q) {
        int i = bse + q;
        if (i < n) sum += cnt[i];
    }
    s[tid] = sum;
    __syncthreads();
    for (int off = 128; off > 0; off >>= 1) {
        if (tid < off) s[tid] += s[tid + off];
        __syncthreads();
    }
    if (tid == 0) bsum[blockIdx.x] = s[0];
}
__global__ __launch_bounds__(1024) void k_scan_bsums(const int* __restrict__ bsum,
                                                     int* __restrict__ boff, int nb,
                                                     int* __restrict__ rowptr, int n, int E) {
    __shared__ int s[1024];
    int tid = threadIdx.x;
    int v = (tid < nb) ? bsum[tid] : 0;
    s[tid] = v;
    __syncthreads();
    for (int off = 1; off < 1024; off <<= 1) {
        int u = (tid >= off) ? s[tid - off] : 0;
        __syncthreads();
        s[tid] += u;
        __syncthreads();
    }
    if (tid < nb) boff[tid] = s[tid] - v;
    if (tid == 0) rowptr[n] = E;
}
__global__ __launch_bounds__(256) void k_scan_apply(const int* __restrict__ cnt,
                                                    const int* __restrict__ boff,
                                                    int* __restrict__ rowptr,
                                                    float* __restrict__ dinv, int n) {
    __shared__ int s[256];
    int tid = threadIdx.x;
    int bse = blockIdx.x * 1024 + tid * 4;
    int c[4];
    int sum = 0;
#pragma unroll
    for (int q = 0; q < 4; ++q) {
        int i = bse + q;
        c[q] = (i < n) ? cnt[i] : 0;
        sum += c[q];
    }
    s[tid] = sum;
    __syncthreads();
    for (int off = 1; off < 256; off <<= 1) {
        int u = (tid >= off) ? s[tid - off] : 0;
        __syncthreads();
        s[tid] += u;
        __syncthreads();
    }
    int run = boff[blockIdx.x] + s[tid] - sum;
#pragma unroll
    for (int q = 0; q < 4; ++q) {
        int i = bse + q;
        if (i < n) {
            rowptr[i] = run;
            run += c[q];
            dinv[i] = rsqrtf((float)(c[q] + 1));
        }
    }
}
__global__ void k_fill_rank(const int* __restrict__ src, const int* __restrict__ dst,
                            const int* __restrict__ rowptr, const int* __restrict__ rank,
                            int* __restrict__ col, int E) {
    int e = blockIdx.x * blockDim.x + threadIdx.x;
    if (e >= E) return;
    int d = dst[e];
    col[rowptr[d] + rank[e]] = src[e];
}

static inline size_t align4(size_t v) { return (v + 3) & ~(size_t)3; }

extern "C" void kernel_launch(void* const* d_in, const int* in_sizes, int n_in,
                              void* d_out, int out_size, void* d_ws, size_t ws_size,
                              hipStream_t stream) {
    const float* x  = (const float*)d_in[0];
    const int*   ei = (const int*)d_in[1];
    const float* W1 = (const float*)d_in[2];
    const float* b1 = (const float*)d_in[3];
    const float* W2 = (const float*)d_in[4];
    const float* b2 = (const float*)d_in[5];
    float* out = (float*)d_out;

    const int n = in_sizes[0] / 16;
    const int E = in_sizes[1] / 2;
    const int* src = ei;
    const int* dst = ei + E;

    const int gn = (n + B - 1) / B;
    const int ge = (E + B - 1) / B;
    const int n8 = n * 8;

    const int NB   = (n + BDIV - 1) / BDIV;      // dst buckets
    const int NBLK = (E + CHUNK - 1) / CHUNK;    // partition blocks

    // ws layout (int units): hists[NB*NBLK] | totals[NB] | base[NB+1] |
    //   rowptr[n+1] | dinv[n] | packed[E] | col[E]
    // after k_bucket_csr, packed region reused: t[2n] at +0, x16[8n] at +2n (16B-aligned)
    size_t o_hists  = 0;
    size_t o_totals = align4(o_hists + (size_t)NB * NBLK);
    size_t o_base   = align4(o_totals + NB);
    size_t o_rowptr = align4(o_base + NB + 1);
    size_t o_dinv   = align4(o_rowptr + n + 1);
    size_t o_packed = align4(o_dinv + n);
    size_t o_col    = align4(o_packed + E);
    size_t need_r5  = (o_col + E) * 4 + 64;

    bool r5_ok = (NB <= NB_MAX) && (NBLK <= 512) && (n <= (1 << 20)) &&
                 ((size_t)(2 * ((n + 1) & ~1) + 8 * n) <= (size_t)E) &&
                 (ws_size >= need_r5);

    if (r5_ok) {
        int* ws = (int*)d_ws;
        int*      hists  = ws + o_hists;
        int*      totals = ws + o_totals;
        int*      base   = ws + o_base;
        int*      rowptr = ws + o_rowptr;
        float*    dinv   = (float*)(ws + o_dinv);
        unsigned* packed = (unsigned*)(ws + o_packed);
        int*      col    = ws + o_col;
        float*    t      = (float*)packed;                       // dead after CSR build
        __half2*  x16    = (__half2*)(packed + 2 * ((n + 1) & ~1));  // 16B-aligned

        k_phist<<<NBLK, 256, 0, stream>>>(dst, hists, E, NB, NBLK);
        k_pscan1<<<NB, 512, 0, stream>>>(hists, totals, NBLK);
        k_pscan2<<<1, 1024, 0, stream>>>(totals, base, NB, rowptr, n, E);
        k_move<<<NBLK, 256, 0, stream>>>(src, dst, hists, base, packed, E, NB, NBLK);
        k_bucket_csr<<<NB, 256, 0, stream>>>(packed, base, rowptr, dinv, col, n);
        k_prep<<<(n8 + 255) / 256, 256, 0, stream>>>(x, dinv, x16, n8);
        k_l1w<<<(n + 3) / 4, 256, 0, stream>>>(x16, rowptr, col, dinv, W1, b1, W2, t, n);
        k_l2w<<<(n + 7) / 8, 256, 0, stream>>>(rowptr, col, dinv, t, b2, out, n);
        return;
    }

    // ---- R3 CSR fallback (global-atomic hist/fill), 16B-aligned scratch tail ----
    const int nb = (n + 1023) / 1024;
    size_t f_cnt    = 0;
    size_t f_rowptr = align4(f_cnt + n);
    size_t f_col    = align4(f_rowptr + n + 1);
    size_t f_dinv   = align4(f_col + E);
    size_t f_bsum   = align4(f_dinv + n);
    size_t f_boff   = align4(f_bsum + nb);
    size_t f_rank   = align4(f_boff + nb);
    size_t rmax = (size_t)E > (size_t)(10 * n + 2) ? (size_t)E : (size_t)(10 * n + 2);
    size_t need_rank = (f_rank + rmax) * 4 + 64;
    if (ws_size >= need_rank && nb <= 1024) {
        int*   ws     = (int*)d_ws;
        int*   cnt    = ws + f_cnt;
        int*   rowptr = ws + f_rowptr;
        int*   col    = ws + f_col;
        float* dinv   = (float*)(ws + f_dinv);
        int*   bsum   = ws + f_bsum;
        int*   boff   = ws + f_boff;
        int*   rank   = ws + f_rank;                 // dead after k_fill_rank
        float* t      = (float*)rank;
        __half2* x16  = (__half2*)(rank + 2 * ((n + 1) & ~1));

        k_zero<<<gn, B, 0, stream>>>(cnt, n);
        k_hist_rank<<<ge, B, 0, stream>>>(dst, cnt, rank, E);
        k_blocksum<<<nb, 256, 0, stream>>>(cnt, bsum, n);
        k_scan_bsums<<<1, 1024, 0, stream>>>(bsum, boff, nb, rowptr, n, E);
        k_scan_apply<<<nb, 256, 0, stream>>>(cnt, boff, rowptr, dinv, n);
        k_fill_rank<<<ge, B, 0, stream>>>(src, dst, rowptr, rank, col, E);
        k_prep<<<(n8 + 255) / 256, 256, 0, stream>>>(x, dinv, x16, n8);
        k_l1w<<<(n + 3) / 4, 256, 0, stream>>>(x16, rowptr, col, dinv, W1, b1, W2, t, n);
        k_l2w<<<(n + 7) / 8, 256, 0, stream>>>(rowptr, col, dinv, t, b2, out, n);
    }
}

// Round 10
// 155.201 us; speedup vs baseline: 1.1540x; 1.1540x over previous
//
#include <hip/hip_runtime.h>
#include <hip/hip_fp16.h>

// GCN 2-layer: out = A(relu(A x W1 + b1) W2) + b2, A = sym-normalized adj + self-loops.
// R10: revert to R8's proven k_l1w/k_l2w shapes (R9's 2-lane/edge fold overhead
// regressed); extend k_l1w to FOUR independent streams (8 loads in flight/lane;
// avg-degree row completes gathers in ~1 iteration). CSR build unchanged from R8.

#define B 256
#define NB_MAX 1024
#define BDIV 128          // nodes per bucket (pow2)
#define BSHIFT 7
#define CHUNK 8192        // edges per partition block

// ---------------- partition: per-block LDS histogram over buckets ----------------
__global__ __launch_bounds__(256) void k_phist(const int* __restrict__ dst,
                                               int* __restrict__ hists,
                                               int E, int NB, int NBLK) {
    __shared__ int h[NB_MAX];
    int tid = threadIdx.x, blk = blockIdx.x;
    for (int b = tid; b < NB; b += 256) h[b] = 0;
    __syncthreads();
    int start = blk * CHUNK;
    int end = min(start + CHUNK, E);
    for (int e = start + tid; e < end; e += 256)
        atomicAdd(&h[((unsigned)dst[e]) >> BSHIFT], 1);
    __syncthreads();
    for (int b = tid; b < NB; b += 256) hists[b * NBLK + blk] = h[b];
}

// per-bucket exclusive scan over NBLK block-counts (NBLK <= 512)
__global__ __launch_bounds__(512) void k_pscan1(int* __restrict__ hists,
                                                int* __restrict__ totals, int NBLK) {
    __shared__ int s[512];
    int b = blockIdx.x, tid = threadIdx.x;
    int v = (tid < NBLK) ? hists[b * NBLK + tid] : 0;
    s[tid] = v;
    __syncthreads();
    for (int off = 1; off < 512; off <<= 1) {
        int u = (tid >= off) ? s[tid - off] : 0;
        __syncthreads();
        s[tid] += u;
        __syncthreads();
    }
    if (tid < NBLK) hists[b * NBLK + tid] = s[tid] - v;  // exclusive within bucket
    if (tid == 511) totals[b] = s[511];
}

// scan bucket totals -> bucket bases (NB <= 1024); base[NB]=E; rowptr[n]=E
__global__ __launch_bounds__(1024) void k_pscan2(const int* __restrict__ totals,
                                                 int* __restrict__ base, int NB,
                                                 int* __restrict__ rowptr, int n, int E) {
    __shared__ int s[1024];
    int tid = threadIdx.x;
    int v = (tid < NB) ? totals[tid] : 0;
    s[tid] = v;
    __syncthreads();
    for (int off = 1; off < 1024; off <<= 1) {
        int u = (tid >= off) ? s[tid - off] : 0;
        __syncthreads();
        s[tid] += u;
        __syncthreads();
    }
    if (tid < NB) base[tid] = s[tid] - v;
    if (tid == 1023) { base[NB] = s[1023]; rowptr[n] = E; }
}

// move edges into bucket regions, LDS-staged for coalesced writes.
__global__ __launch_bounds__(256) void k_move(const int* __restrict__ src,
                                              const int* __restrict__ dst,
                                              const int* __restrict__ hists,
                                              const int* __restrict__ base,
                                              unsigned* __restrict__ packed,
                                              int E, int NB, int NBLK) {
    __shared__ unsigned stage[CHUNK];            // 32 KB
    __shared__ unsigned short stage_b[CHUNK];    // 16 KB
    __shared__ int lh[NB_MAX];
    __shared__ int lexc[NB_MAX];
    __shared__ int gb[NB_MAX];
    __shared__ int part[256];
    int tid = threadIdx.x, blk = blockIdx.x;
    int start = blk * CHUNK;
    int end = min(start + CHUNK, E);
    for (int b = tid; b < NB; b += 256) lh[b] = 0;
    __syncthreads();
    for (int e = start + tid; e < end; e += 256)
        atomicAdd(&lh[((unsigned)dst[e]) >> BSHIFT], 1);
    __syncthreads();
    int t4 = tid * 4;
    int a0 = 0, a1 = 0, a2 = 0, a3 = 0;
    if (t4 + 0 < NB) a0 = lh[t4 + 0];
    if (t4 + 1 < NB) a1 = lh[t4 + 1];
    if (t4 + 2 < NB) a2 = lh[t4 + 2];
    if (t4 + 3 < NB) a3 = lh[t4 + 3];
    int sum = a0 + a1 + a2 + a3;
    part[tid] = sum;
    __syncthreads();
    for (int off = 1; off < 256; off <<= 1) {
        int u = (tid >= off) ? part[tid - off] : 0;
        __syncthreads();
        part[tid] += u;
        __syncthreads();
    }
    int run = part[tid] - sum;
    if (t4 + 0 < NB) { lexc[t4 + 0] = run; run += a0; }
    if (t4 + 1 < NB) { lexc[t4 + 1] = run; run += a1; }
    if (t4 + 2 < NB) { lexc[t4 + 2] = run; run += a2; }
    if (t4 + 3 < NB) { lexc[t4 + 3] = run; run += a3; }
    __syncthreads();
    for (int b = tid; b < NB; b += 256) {
        lh[b] = lexc[b];
        gb[b] = base[b] + hists[b * NBLK + blk] - lexc[b];
    }
    __syncthreads();
    for (int e = start + tid; e < end; e += 256) {
        unsigned d = (unsigned)dst[e];
        int b = d >> BSHIFT;
        int r = atomicAdd(&lh[b], 1);
        stage[r] = (unsigned)src[e] | ((d & (BDIV - 1u)) << 20);
        stage_b[r] = (unsigned short)b;
    }
    __syncthreads();
    int cnt = end - start;
    for (int i = tid; i < cnt; i += 256)
        packed[gb[stage_b[i]] + i] = stage[i];
}

// per-bucket: LDS hist over 128 local nodes -> scan -> rowptr/dinv + place col
__global__ __launch_bounds__(256) void k_bucket_csr(const unsigned* __restrict__ packed,
                                                    const int* __restrict__ base,
                                                    int* __restrict__ rowptr,
                                                    float* __restrict__ dinv,
                                                    int* __restrict__ col, int n) {
    __shared__ int lcnt[BDIV];
    __shared__ int lexc[BDIV];
    int b = blockIdx.x, tid = threadIdx.x;
    if (tid < BDIV) lcnt[tid] = 0;
    __syncthreads();
    int s0 = base[b], s1 = base[b + 1];
    for (int i = s0 + tid; i < s1; i += 256)
        atomicAdd(&lcnt[packed[i] >> 20], 1);
    __syncthreads();
    int v = (tid < BDIV) ? lcnt[tid] : 0;
    if (tid < BDIV) lexc[tid] = v;
    __syncthreads();
    for (int off = 1; off < BDIV; off <<= 1) {
        int u = (tid < BDIV && tid >= off) ? lexc[tid - off] : 0;
        __syncthreads();
        if (tid < BDIV) lexc[tid] += u;
        __syncthreads();
    }
    if (tid < BDIV) {
        lexc[tid] -= v;  // exclusive
        int node = b * BDIV + tid;
        if (node < n) {
            rowptr[node] = s0 + lexc[tid];
            dinv[node] = rsqrtf((float)(v + 1));  // +1 self-loop
        }
        lcnt[tid] = 0;  // reuse as fill cursor
    }
    __syncthreads();
    for (int i = s0 + tid; i < s1; i += 256) {
        unsigned u = packed[i];
        int l = (int)(u >> 20);
        int pos = s0 + lexc[l] + atomicAdd(&lcnt[l], 1);
        col[pos] = (int)(u & 0xFFFFFu);
    }
}

// ---------------- x16 = fp16(x * dinv): L2-resident gather operand ----------------
__global__ void k_prep(const float* __restrict__ x, const float* __restrict__ dinv,
                       __half2* __restrict__ x16, int n8) {
    int g = blockIdx.x * blockDim.x + threadIdx.x;  // one half2 (2 feats)
    if (g >= n8) return;
    float d = dinv[g >> 3];
    float2 v = ((const float2*)x)[g];
    x16[g] = __float22half2_rn(make_float2(v.x * d, v.y * d));
}

// ---------------- layer 1: wave-per-row fp16 gather + in-wave fused MLP ----------
// lane = (h = lane&7 feat-pair, eg = lane>>3 edge-group). FOUR independent streams
// (j, j+8, j+16, j+24; stride 32) + col prefetch -> 8 loads in flight per lane; an
// avg-degree row (deg~32) completes its gather phase in ~1 iteration.
__global__ __launch_bounds__(256) void k_l1w(const __half2* __restrict__ x16,
                                             const int* __restrict__ rowptr,
                                             const int* __restrict__ col,
                                             const float* __restrict__ dinv,
                                             const float* __restrict__ W1,
                                             const float* __restrict__ b1,
                                             const float* __restrict__ W2,
                                             float* __restrict__ t, int n) {
    __shared__ float sW1[512], sW2[64], sb1[32];
    int tid = threadIdx.x;
    for (int k = tid; k < 512; k += 256) sW1[k] = W1[k];
    if (tid < 64) sW2[tid] = W2[tid];
    if (tid < 32) sb1[tid] = b1[tid];
    __syncthreads();
    int lane = tid & 63;
    int r = blockIdx.x * 4 + (tid >> 6);
    if (r >= n) return;
    int h = lane & 7, eg = lane >> 3;
    float dr = dinv[r];
    int beg = rowptr[r], fin = rowptr[r + 1];
    float s0 = 0.f, s1 = 0.f;
    if (eg == 0) {  // self-loop: x16[r] = x*dinv_r, *dr later -> x*dinv_r^2
        float2 f = __half22float2(x16[(size_t)r * 8 + h]);
        s0 = f.x; s1 = f.y;
    }
    int jA = beg + eg, jB = jA + 8, jC = jA + 16, jD = jA + 24;
    int sA = (jA < fin) ? col[jA] : -1;
    int sB = (jB < fin) ? col[jB] : -1;
    int sC = (jC < fin) ? col[jC] : -1;
    int sD = (jD < fin) ? col[jD] : -1;
    while (sA >= 0) {
        float2 fA = __half22float2(x16[(size_t)sA * 8 + h]);
        float2 fB = make_float2(0.f, 0.f);
        float2 fC = make_float2(0.f, 0.f);
        float2 fD = make_float2(0.f, 0.f);
        if (sB >= 0) fB = __half22float2(x16[(size_t)sB * 8 + h]);
        if (sC >= 0) fC = __half22float2(x16[(size_t)sC * 8 + h]);
        if (sD >= 0) fD = __half22float2(x16[(size_t)sD * 8 + h]);
        jA += 32; jB += 32; jC += 32; jD += 32;
        sA = (jA < fin) ? col[jA] : -1;
        sB = (jB < fin) ? col[jB] : -1;
        sC = (jC < fin) ? col[jC] : -1;
        sD = (jD < fin) ? col[jD] : -1;
        s0 += (fA.x + fB.x) + (fC.x + fD.x);
        s1 += (fA.y + fB.y) + (fC.y + fD.y);
    }
    s0 += __shfl_xor(s0, 8);  s1 += __shfl_xor(s1, 8);
    s0 += __shfl_xor(s0, 16); s1 += __shfl_xor(s1, 16);
    s0 += __shfl_xor(s0, 32); s1 += __shfl_xor(s1, 32);
    s0 *= dr; s1 *= dr;  // agg[2h], agg[2h+1] in every lane
    int j32 = lane & 31;
    float hv = sb1[j32];
#pragma unroll
    for (int k = 0; k < 16; ++k) {
        float a = __shfl((k & 1) ? s1 : s0, k >> 1);
        hv = fmaf(a, sW1[k * 32 + j32], hv);
    }
    hv = fmaxf(hv, 0.f);
    float p = hv * sW2[j32 * 2 + (lane >> 5)];  // lanes<32 -> t0, lanes>=32 -> t1
#pragma unroll
    for (int off = 1; off <= 16; off <<= 1) p += __shfl_xor(p, off);
    if ((lane & 31) == 0) t[(size_t)r * 2 + (lane >> 5)] = p * dr;  // pre-scaled
}

// ---------------- layer 2: 8 lanes per node, dual-stream pure-add loop ----------
__global__ __launch_bounds__(256) void k_l2w(const int* __restrict__ rowptr,
                                             const int* __restrict__ col,
                                             const float* __restrict__ dinv,
                                             const float* __restrict__ ts,
                                             const float* __restrict__ b2,
                                             float* __restrict__ out, int n) {
    int g = blockIdx.x * 256 + threadIdx.x;
    int i = g >> 3, q = g & 7;
    if (i >= n) return;
    float di = dinv[i];
    int beg = rowptr[i], fin = rowptr[i + 1];
    float a0 = 0.f, a1 = 0.f;
    if (q == 0) {  // self: ts[i] = t*dinv_i; *di at end -> t*dinv_i^2
        float2 tv = *(const float2*)(ts + (size_t)i * 2);
        a0 = tv.x; a1 = tv.y;
    }
    int jA = beg + q, jB = jA + 8;
    int sA = (jA < fin) ? col[jA] : -1;
    int sB = (jB < fin) ? col[jB] : -1;
    while (sA >= 0) {
        float2 tA = *(const float2*)(ts + (size_t)sA * 2);
        float2 tB = make_float2(0.f, 0.f);
        if (sB >= 0) tB = *(const float2*)(ts + (size_t)sB * 2);
        jA += 16; jB += 16;
        sA = (jA < fin) ? col[jA] : -1;
        sB = (jB < fin) ? col[jB] : -1;
        a0 += tA.x + tB.x;
        a1 += tA.y + tB.y;
    }
    a0 += __shfl_xor(a0, 1); a1 += __shfl_xor(a1, 1);
    a0 += __shfl_xor(a0, 2); a1 += __shfl_xor(a1, 2);
    a0 += __shfl_xor(a0, 4); a1 += __shfl_xor(a1, 4);
    if (q == 0) {
        out[(size_t)i * 2 + 0] = fmaf(a0, di, b2[0]);
        out[(size_t)i * 2 + 1] = fmaf(a1, di, b2[1]);
    }
}

// ---------------- R3 CSR fallback kernels (global-atomic build) ----------------

__global__ void k_zero(int* __restrict__ cnt, int n) {
    int i = blockIdx.x * blockDim.x + threadIdx.x;
    if (i < n) cnt[i] = 0;
}
__global__ void k_hist_rank(const int* __restrict__ dst, int* __restrict__ cnt,
                            int* __restrict__ rank, int E) {
    int e = blockIdx.x * blockDim.x + threadIdx.x;
    if (e < E) rank[e] = atomicAdd(&cnt[dst[e]], 1);
}
__global__ __launch_bounds__(256) void k_blocksum(const int* __restrict__ cnt,
                                                  int* __restrict__ bsum, int n) {
    __shared__ int s[256];
    int tid = threadIdx.x;
    int bse = blockIdx.x * 1024 + tid * 4;
    int sum = 0;
#pragma unroll
    for (int q = 0; q < 4; ++q) {
        int i = bse + q;
        if (i < n) sum += cnt[i];
    }
    s[tid] = sum;
    __syncthreads();
    for (int off = 128; off > 0; off >>= 1) {
        if (tid < off) s[tid] += s[tid + off];
        __syncthreads();
    }
    if (tid == 0) bsum[blockIdx.x] = s[0];
}
__global__ __launch_bounds__(1024) void k_scan_bsums(const int* __restrict__ bsum,
                                                     int* __restrict__ boff, int nb,
                                                     int* __restrict__ rowptr, int n, int E) {
    __shared__ int s[1024];
    int tid = threadIdx.x;
    int v = (tid < nb) ? bsum[tid] : 0;
    s[tid] = v;
    __syncthreads();
    for (int off = 1; off < 1024; off <<= 1) {
        int u = (tid >= off) ? s[tid - off] : 0;
        __syncthreads();
        s[tid] += u;
        __syncthreads();
    }
    if (tid < nb) boff[tid] = s[tid] - v;
    if (tid == 0) rowptr[n] = E;
}
__global__ __launch_bounds__(256) void k_scan_apply(const int* __restrict__ cnt,
                                                    const int* __restrict__ boff,
                                                    int* __restrict__ rowptr,
                                                    float* __restrict__ dinv, int n) {
    __shared__ int s[256];
    int tid = threadIdx.x;
    int bse = blockIdx.x * 1024 + tid * 4;
    int c[4];
    int sum = 0;
#pragma unroll
    for (int q = 0; q < 4; ++q) {
        int i = bse + q;
        c[q] = (i < n) ? cnt[i] : 0;
        sum += c[q];
    }
    s[tid] = sum;
    __syncthreads();
    for (int off = 1; off < 256; off <<= 1) {
        int u = (tid >= off) ? s[tid - off] : 0;
        __syncthreads();
        s[tid] += u;
        __syncthreads();
    }
    int run = boff[blockIdx.x] + s[tid] - sum;
#pragma unroll
    for (int q = 0; q < 4; ++q) {
        int i = bse + q;
        if (i < n) {
            rowptr[i] = run;
            run += c[q];
            dinv[i] = rsqrtf((float)(c[q] + 1));
        }
    }
}
__global__ void k_fill_rank(const int* __restrict__ src, const int* __restrict__ dst,
                            const int* __restrict__ rowptr, const int* __restrict__ rank,
                            int* __restrict__ col, int E) {
    int e = blockIdx.x * blockDim.x + threadIdx.x;
    if (e >= E) return;
    int d = dst[e];
    col[rowptr[d] + rank[e]] = src[e];
}

static inline size_t align4(size_t v) { return (v + 3) & ~(size_t)3; }

extern "C" void kernel_launch(void* const* d_in, const int* in_sizes, int n_in,
                              void* d_out, int out_size, void* d_ws, size_t ws_size,
                              hipStream_t stream) {
    const float* x  = (const float*)d_in[0];
    const int*   ei = (const int*)d_in[1];
    const float* W1 = (const float*)d_in[2];
    const float* b1 = (const float*)d_in[3];
    const float* W2 = (const float*)d_in[4];
    const float* b2 = (const float*)d_in[5];
    float* out = (float*)d_out;

    const int n = in_sizes[0] / 16;
    const int E = in_sizes[1] / 2;
    const int* src = ei;
    const int* dst = ei + E;

    const int gn = (n + B - 1) / B;
    const int ge = (E + B - 1) / B;
    const int n8 = n * 8;

    const int NB   = (n + BDIV - 1) / BDIV;      // dst buckets
    const int NBLK = (E + CHUNK - 1) / CHUNK;    // partition blocks

    // ws layout (int units): hists[NB*NBLK] | totals[NB] | base[NB+1] |
    //   rowptr[n+1] | dinv[n] | packed[E] | col[E]
    // after k_bucket_csr, packed region reused: t[2n] at +0, x16[8n] at +2n (16B-aligned)
    size_t o_hists  = 0;
    size_t o_totals = align4(o_hists + (size_t)NB * NBLK);
    size_t o_base   = align4(o_totals + NB);
    size_t o_rowptr = align4(o_base + NB + 1);
    size_t o_dinv   = align4(o_rowptr + n + 1);
    size_t o_packed = align4(o_dinv + n);
    size_t o_col    = align4(o_packed + E);
    size_t need_r5  = (o_col + E) * 4 + 64;

    bool r5_ok = (NB <= NB_MAX) && (NBLK <= 512) && (n <= (1 << 20)) &&
                 ((size_t)(2 * ((n + 1) & ~1) + 8 * n) <= (size_t)E) &&
                 (ws_size >= need_r5);

    if (r5_ok) {
        int* ws = (int*)d_ws;
        int*      hists  = ws + o_hists;
        int*      totals = ws + o_totals;
        int*      base   = ws + o_base;
        int*      rowptr = ws + o_rowptr;
        float*    dinv   = (float*)(ws + o_dinv);
        unsigned* packed = (unsigned*)(ws + o_packed);
        int*      col    = ws + o_col;
        float*    t      = (float*)packed;                       // dead after CSR build
        __half2*  x16    = (__half2*)(packed + 2 * ((n + 1) & ~1));  // 16B-aligned

        k_phist<<<NBLK, 256, 0, stream>>>(dst, hists, E, NB, NBLK);
        k_pscan1<<<NB, 512, 0, stream>>>(hists, totals, NBLK);
        k_pscan2<<<1, 1024, 0, stream>>>(totals, base, NB, rowptr, n, E);
        k_move<<<NBLK, 256, 0, stream>>>(src, dst, hists, base, packed, E, NB, NBLK);
        k_bucket_csr<<<NB, 256, 0, stream>>>(packed, base, rowptr, dinv, col, n);
        k_prep<<<(n8 + 255) / 256, 256, 0, stream>>>(x, dinv, x16, n8);
        k_l1w<<<(n + 3) / 4, 256, 0, stream>>>(x16, rowptr, col, dinv, W1, b1, W2, t, n);
        k_l2w<<<(8 * n + 255) / 256, 256, 0, stream>>>(rowptr, col, dinv, t, b2, out, n);
        return;
    }

    // ---- R3 CSR fallback (global-atomic hist/fill), 16B-aligned scratch tail ----
    const int nb = (n + 1023) / 1024;
    size_t f_cnt    = 0;
    size_t f_rowptr = align4(f_cnt + n);
    size_t f_col    = align4(f_rowptr + n + 1);
    size_t f_dinv   = align4(f_col + E);
    size_t f_bsum   = align4(f_dinv + n);
    size_t f_boff   = align4(f_bsum + nb);
    size_t f_rank   = align4(f_boff + nb);
    size_t rmax = (size_t)E > (size_t)(10 * n + 2) ? (size_t)E : (size_t)(10 * n + 2);
    size_t need_rank = (f_rank + rmax) * 4 + 64;
    if (ws_size >= need_rank && nb <= 1024) {
        int*   ws     = (int*)d_ws;
        int*   cnt    = ws + f_cnt;
        int*   rowptr = ws + f_rowptr;
        int*   col    = ws + f_col;
        float* dinv   = (float*)(ws + f_dinv);
        int*   bsum   = ws + f_bsum;
        int*   boff   = ws + f_boff;
        int*   rank   = ws + f_rank;                 // dead after k_fill_rank
        float* t      = (float*)rank;
        __half2* x16  = (__half2*)(rank + 2 * ((n + 1) & ~1));

        k_zero<<<gn, B, 0, stream>>>(cnt, n);
        k_hist_rank<<<ge, B, 0, stream>>>(dst, cnt, rank, E);
        k_blocksum<<<nb, 256, 0, stream>>>(cnt, bsum, n);
        k_scan_bsums<<<1, 1024, 0, stream>>>(bsum, boff, nb, rowptr, n, E);
        k_scan_apply<<<nb, 256, 0, stream>>>(cnt, boff, rowptr, dinv, n);
        k_fill_rank<<<ge, B, 0, stream>>>(src, dst, rowptr, rank, col, E);
        k_prep<<<(n8 + 255) / 256, 256, 0, stream>>>(x, dinv, x16, n8);
        k_l1w<<<(n + 3) / 4, 256, 0, stream>>>(x16, rowptr, col, dinv, W1, b1, W2, t, n);
        k_l2w<<<(8 * n + 255) / 256, 256, 0, stream>>>(rowptr, col, dinv, t, b2, out, n);
    }
}

// Round 11
// 148.469 us; speedup vs baseline: 1.2064x; 1.0453x over previous
//
#include <hip/hip_runtime.h>
#include <hip/hip_fp16.h>

// GCN 2-layer: out = A(relu(A x W1 + b1) W2) + b2, A = sym-normalized adj + self-loops.
// R11: branch-free gathers. R10 showed stream-count saturation (65us flat, VALUBusy
// 47%): the divergent per-stream guards (cndmask/exec juggling) are the cost. Pad each
// CSR row to a multiple of 8 with sentinel index n (zero row) -> inner loops are
// uniform-trip-count, guard-free; compiler pipelines the independent loads.

#define B 256
#define NB_MAX 1024
#define BDIV 128          // nodes per bucket (pow2)
#define BSHIFT 7
#define CHUNK 8192        // edges per partition block
#define RI_MASK 0x7FFFFFu // rowinfo: start in low 23 bits, trips in high 9

// ---------------- partition: per-block LDS histogram over buckets ----------------
__global__ __launch_bounds__(256) void k_phist(const int* __restrict__ dst,
                                               int* __restrict__ hists,
                                               int E, int NB, int NBLK) {
    __shared__ int h[NB_MAX];
    int tid = threadIdx.x, blk = blockIdx.x;
    for (int b = tid; b < NB; b += 256) h[b] = 0;
    __syncthreads();
    int start = blk * CHUNK;
    int end = min(start + CHUNK, E);
    for (int e = start + tid; e < end; e += 256)
        atomicAdd(&h[((unsigned)dst[e]) >> BSHIFT], 1);
    __syncthreads();
    for (int b = tid; b < NB; b += 256) hists[b * NBLK + blk] = h[b];
}

// per-bucket exclusive scan over NBLK block-counts (NBLK <= 512)
__global__ __launch_bounds__(512) void k_pscan1(int* __restrict__ hists,
                                                int* __restrict__ totals, int NBLK) {
    __shared__ int s[512];
    int b = blockIdx.x, tid = threadIdx.x;
    int v = (tid < NBLK) ? hists[b * NBLK + tid] : 0;
    s[tid] = v;
    __syncthreads();
    for (int off = 1; off < 512; off <<= 1) {
        int u = (tid >= off) ? s[tid - off] : 0;
        __syncthreads();
        s[tid] += u;
        __syncthreads();
    }
    if (tid < NBLK) hists[b * NBLK + tid] = s[tid] - v;  // exclusive within bucket
    if (tid == 511) totals[b] = s[511];
}

// scan bucket totals -> bucket bases (NB <= 1024); base[NB]=E
__global__ __launch_bounds__(1024) void k_pscan2(const int* __restrict__ totals,
                                                 int* __restrict__ base, int NB, int E) {
    __shared__ int s[1024];
    int tid = threadIdx.x;
    int v = (tid < NB) ? totals[tid] : 0;
    s[tid] = v;
    __syncthreads();
    for (int off = 1; off < 1024; off <<= 1) {
        int u = (tid >= off) ? s[tid - off] : 0;
        __syncthreads();
        s[tid] += u;
        __syncthreads();
    }
    if (tid < NB) base[tid] = s[tid] - v;
    if (tid == 1023) base[NB] = s[1023];
}

// move edges into bucket regions, LDS-staged for coalesced writes.
__global__ __launch_bounds__(256) void k_move(const int* __restrict__ src,
                                              const int* __restrict__ dst,
                                              const int* __restrict__ hists,
                                              const int* __restrict__ base,
                                              unsigned* __restrict__ packed,
                                              int E, int NB, int NBLK) {
    __shared__ unsigned stage[CHUNK];            // 32 KB
    __shared__ unsigned short stage_b[CHUNK];    // 16 KB
    __shared__ int lh[NB_MAX];
    __shared__ int lexc[NB_MAX];
    __shared__ int gb[NB_MAX];
    __shared__ int part[256];
    int tid = threadIdx.x, blk = blockIdx.x;
    int start = blk * CHUNK;
    int end = min(start + CHUNK, E);
    for (int b = tid; b < NB; b += 256) lh[b] = 0;
    __syncthreads();
    for (int e = start + tid; e < end; e += 256)
        atomicAdd(&lh[((unsigned)dst[e]) >> BSHIFT], 1);
    __syncthreads();
    int t4 = tid * 4;
    int a0 = 0, a1 = 0, a2 = 0, a3 = 0;
    if (t4 + 0 < NB) a0 = lh[t4 + 0];
    if (t4 + 1 < NB) a1 = lh[t4 + 1];
    if (t4 + 2 < NB) a2 = lh[t4 + 2];
    if (t4 + 3 < NB) a3 = lh[t4 + 3];
    int sum = a0 + a1 + a2 + a3;
    part[tid] = sum;
    __syncthreads();
    for (int off = 1; off < 256; off <<= 1) {
        int u = (tid >= off) ? part[tid - off] : 0;
        __syncthreads();
        part[tid] += u;
        __syncthreads();
    }
    int run = part[tid] - sum;
    if (t4 + 0 < NB) { lexc[t4 + 0] = run; run += a0; }
    if (t4 + 1 < NB) { lexc[t4 + 1] = run; run += a1; }
    if (t4 + 2 < NB) { lexc[t4 + 2] = run; run += a2; }
    if (t4 + 3 < NB) { lexc[t4 + 3] = run; run += a3; }
    __syncthreads();
    for (int b = tid; b < NB; b += 256) {
        lh[b] = lexc[b];
        gb[b] = base[b] + hists[b * NBLK + blk] - lexc[b];
    }
    __syncthreads();
    for (int e = start + tid; e < end; e += 256) {
        unsigned d = (unsigned)dst[e];
        int b = d >> BSHIFT;
        int r = atomicAdd(&lh[b], 1);
        stage[r] = (unsigned)src[e] | ((d & (BDIV - 1u)) << 20);
        stage_b[r] = (unsigned short)b;
    }
    __syncthreads();
    int cnt = end - start;
    for (int i = tid; i < cnt; i += 256)
        packed[gb[stage_b[i]] + i] = stage[i];
}

// per-bucket: LDS hist -> PADDED scan (mult of 8) -> rowinfo/dinv + place col + sentinels.
// col region for bucket b starts at base[b] + 1024*b (1024 = worst-case pad per bucket).
__global__ __launch_bounds__(256) void k_bucket_csr(const unsigned* __restrict__ packed,
                                                    const int* __restrict__ base,
                                                    unsigned* __restrict__ rowinfo,
                                                    float* __restrict__ dinv,
                                                    int* __restrict__ col, int n) {
    __shared__ int lcnt[BDIV];
    __shared__ int plexc[BDIV];
    int b = blockIdx.x, tid = threadIdx.x;
    if (tid < BDIV) lcnt[tid] = 0;
    __syncthreads();
    int s0 = base[b], s1 = base[b + 1];
    for (int i = s0 + tid; i < s1; i += 256)
        atomicAdd(&lcnt[packed[i] >> 20], 1);
    __syncthreads();
    int v = (tid < BDIV) ? lcnt[tid] : 0;
    int vp = (v + 7) & ~7;  // padded degree
    if (tid < BDIV) plexc[tid] = vp;
    __syncthreads();
    for (int off = 1; off < BDIV; off <<= 1) {
        int u = (tid < BDIV && tid >= off) ? plexc[tid - off] : 0;
        __syncthreads();
        if (tid < BDIV) plexc[tid] += u;
        __syncthreads();
    }
    int cb = s0 + 1024 * b;  // padded col base for this bucket
    if (tid < BDIV) {
        plexc[tid] -= vp;  // exclusive padded offset
        int node = b * BDIV + tid;
        if (node < n) {
            rowinfo[node] = (unsigned)(cb + plexc[tid]) | ((unsigned)(vp >> 3) << 23);
            dinv[node] = rsqrtf((float)(v + 1));  // +1 self-loop
        }
        lcnt[tid] = 0;  // reuse as fill cursor
    }
    __syncthreads();
    for (int i = s0 + tid; i < s1; i += 256) {
        unsigned u = packed[i];
        int l = (int)(u >> 20);
        int pos = cb + plexc[l] + atomicAdd(&lcnt[l], 1);
        col[pos] = (int)(u & 0xFFFFFu);
    }
    __syncthreads();
    if (tid < BDIV) {
        int st = cb + plexc[tid];
        for (int k = v; k < vp; ++k) col[st + k] = n;  // sentinel -> zero row
    }
}

// ---------------- x16 = fp16(x * dinv) + zero sentinel row / sentinel t ----------
__global__ void k_prep(const float* __restrict__ x, const float* __restrict__ dinv,
                       __half2* __restrict__ x16, float* __restrict__ t, int n8) {
    int g = blockIdx.x * blockDim.x + threadIdx.x;  // one half2 (2 feats)
    if (g < n8) {
        float d = dinv[g >> 3];
        float2 v = ((const float2*)x)[g];
        x16[g] = __float22half2_rn(make_float2(v.x * d, v.y * d));
    } else if (g < n8 + 8) {
        x16[g] = __float22half2_rn(make_float2(0.f, 0.f));  // sentinel row n
        if (g == n8) {  // sentinel t row n
            t[(n8 >> 3) * 2 + 0] = 0.f;
            t[(n8 >> 3) * 2 + 1] = 0.f;
        }
    }
}

// ---------------- layer 1: wave-per-row, branch-free padded gather + fused MLP ---
// lane = (h = lane&7 feat-pair, eg = lane>>3 edge-group). trips is wave-uniform;
// loop body has NO per-lane guards (sentinel col -> zero row).
__global__ __launch_bounds__(256) void k_l1w(const __half2* __restrict__ x16,
                                             const unsigned* __restrict__ rowinfo,
                                             const int* __restrict__ col,
                                             const float* __restrict__ dinv,
                                             const float* __restrict__ W1,
                                             const float* __restrict__ b1,
                                             const float* __restrict__ W2,
                                             float* __restrict__ t, int n) {
    __shared__ float sW1[512], sW2[64], sb1[32];
    int tid = threadIdx.x;
    for (int k = tid; k < 512; k += 256) sW1[k] = W1[k];
    if (tid < 64) sW2[tid] = W2[tid];
    if (tid < 32) sb1[tid] = b1[tid];
    __syncthreads();
    int lane = tid & 63;
    int r = blockIdx.x * 4 + (tid >> 6);
    if (r >= n) return;
    int h = lane & 7, eg = lane >> 3;
    float dr = dinv[r];
    unsigned ri = rowinfo[r];
    int j = (int)(ri & RI_MASK) + eg;
    int trips = (int)(ri >> 23);
    float s0 = 0.f, s1 = 0.f;
    if (eg == 0) {  // self-loop: x16[r] = x*dinv_r, *dr later -> x*dinv_r^2
        float2 f = __half22float2(x16[(size_t)r * 8 + h]);
        s0 = f.x; s1 = f.y;
    }
#pragma unroll 4
    for (int it = 0; it < trips; ++it, j += 8) {
        int sc = col[j];
        float2 f = __half22float2(x16[(size_t)sc * 8 + h]);
        s0 += f.x; s1 += f.y;
    }
    s0 += __shfl_xor(s0, 8);  s1 += __shfl_xor(s1, 8);
    s0 += __shfl_xor(s0, 16); s1 += __shfl_xor(s1, 16);
    s0 += __shfl_xor(s0, 32); s1 += __shfl_xor(s1, 32);
    s0 *= dr; s1 *= dr;  // agg[2h], agg[2h+1] in every lane
    int j32 = lane & 31;
    float hv = sb1[j32];
#pragma unroll
    for (int k = 0; k < 16; ++k) {
        float a = __shfl((k & 1) ? s1 : s0, k >> 1);
        hv = fmaf(a, sW1[k * 32 + j32], hv);
    }
    hv = fmaxf(hv, 0.f);
    float p = hv * sW2[j32 * 2 + (lane >> 5)];  // lanes<32 -> t0, lanes>=32 -> t1
#pragma unroll
    for (int off = 1; off <= 16; off <<= 1) p += __shfl_xor(p, off);
    if ((lane & 31) == 0) t[(size_t)r * 2 + (lane >> 5)] = p * dr;  // pre-scaled
}

// ---------------- layer 2: 8 lanes per node, branch-free padded loop ------------
__global__ __launch_bounds__(256) void k_l2w(const unsigned* __restrict__ rowinfo,
                                             const int* __restrict__ col,
                                             const float* __restrict__ dinv,
                                             const float* __restrict__ ts,
                                             const float* __restrict__ b2,
                                             float* __restrict__ out, int n) {
    int g = blockIdx.x * 256 + threadIdx.x;
    int i = g >> 3, q = g & 7;
    if (i >= n) return;
    float di = dinv[i];
    unsigned ri = rowinfo[i];
    int j = (int)(ri & RI_MASK) + q;
    int trips = (int)(ri >> 23);
    float a0 = 0.f, a1 = 0.f;
    if (q == 0) {  // self: ts[i] = t*dinv_i; *di at end -> t*dinv_i^2
        float2 tv = *(const float2*)(ts + (size_t)i * 2);
        a0 = tv.x; a1 = tv.y;
    }
#pragma unroll 4
    for (int it = 0; it < trips; ++it, j += 8) {
        int sc = col[j];
        float2 tv = *(const float2*)(ts + (size_t)sc * 2);
        a0 += tv.x; a1 += tv.y;
    }
    a0 += __shfl_xor(a0, 1); a1 += __shfl_xor(a1, 1);
    a0 += __shfl_xor(a0, 2); a1 += __shfl_xor(a1, 2);
    a0 += __shfl_xor(a0, 4); a1 += __shfl_xor(a1, 4);
    if (q == 0) {
        out[(size_t)i * 2 + 0] = fmaf(a0, di, b2[0]);
        out[(size_t)i * 2 + 1] = fmaf(a1, di, b2[1]);
    }
}

// ---------------- fallback (global-atomic build, padded) ----------------

__global__ void k_zero(int* __restrict__ cnt, int n) {
    int i = blockIdx.x * blockDim.x + threadIdx.x;
    if (i < n) cnt[i] = 0;
}
__global__ void k_hist_rank(const int* __restrict__ dst, int* __restrict__ cnt,
                            int* __restrict__ rank, int E) {
    int e = blockIdx.x * blockDim.x + threadIdx.x;
    if (e < E) rank[e] = atomicAdd(&cnt[dst[e]], 1);
}
__global__ __launch_bounds__(256) void k_blocksum(const int* __restrict__ cnt,
                                                  int* __restrict__ bsum, int n) {
    __shared__ int s[256];
    int tid = threadIdx.x;
    int bse = blockIdx.x * 1024 + tid * 4;
    int sum = 0;
#pragma unroll
    for (int q = 0; q < 4; ++q) {
        int i = bse + q;
        if (i < n) sum += (cnt[i] + 7) & ~7;  // padded
    }
    s[tid] = sum;
    __syncthreads();
    for (int off = 128; off > 0; off >>= 1) {
        if (tid < off) s[tid] += s[tid + off];
        __syncthreads();
    }
    if (tid == 0) bsum[blockIdx.x] = s[0];
}
__global__ __launch_bounds__(1024) void k_scan_bsums(const int* __restrict__ bsum,
                                                     int* __restrict__ boff, int nb) {
    __shared__ int s[1024];
    int tid = threadIdx.x;
    int v = (tid < nb) ? bsum[tid] : 0;
    s[tid] = v;
    __syncthreads();
    for (int off = 1; off < 1024; off <<= 1) {
        int u = (tid >= off) ? s[tid - off] : 0;
        __syncthreads();
        s[tid] += u;
        __syncthreads();
    }
    if (tid < nb) boff[tid] = s[tid] - v;
}
__global__ __launch_bounds__(256) void k_scan_apply(const int* __restrict__ cnt,
                                                    const int* __restrict__ boff,
                                                    unsigned* __restrict__ rowinfo,
                                                    float* __restrict__ dinv, int n) {
    __shared__ int s[256];
    int tid = threadIdx.x;
    int bse = blockIdx.x * 1024 + tid * 4;
    int c[4];
    int sum = 0;
#pragma unroll
    for (int q = 0; q < 4; ++q) {
        int i = bse + q;
        c[q] = (i < n) ? ((cnt[i] + 7) & ~7) : 0;
        sum += c[q];
    }
    s[tid] = sum;
    __syncthreads();
    for (int off = 1; off < 256; off <<= 1) {
        int u = (tid >= off) ? s[tid - off] : 0;
        __syncthreads();
        s[tid] += u;
        __syncthreads();
    }
    int run = boff[blockIdx.x] + s[tid] - sum;
#pragma unroll
    for (int q = 0; q < 4; ++q) {
        int i = bse + q;
        if (i < n) {
            rowinfo[i] = (unsigned)run | ((unsigned)(c[q] >> 3) << 23);
            run += c[q];
            dinv[i] = rsqrtf((float)(cnt[i] + 1));
        }
    }
}
__global__ void k_fill_rank(const int* __restrict__ src, const int* __restrict__ dst,
                            const unsigned* __restrict__ rowinfo,
                            const int* __restrict__ rank,
                            int* __restrict__ col, int E) {
    int e = blockIdx.x * blockDim.x + threadIdx.x;
    if (e >= E) return;
    int d = dst[e];
    col[(rowinfo[d] & RI_MASK) + rank[e]] = src[e];
}
__global__ void k_pad_sent(const unsigned* __restrict__ rowinfo,
                           const int* __restrict__ cnt,
                           int* __restrict__ col, int n) {
    int i = blockIdx.x * blockDim.x + threadIdx.x;
    if (i >= n) return;
    int st = (int)(rowinfo[i] & RI_MASK);
    int v = cnt[i], vp = (v + 7) & ~7;
    for (int k = v; k < vp; ++k) col[st + k] = n;
}

static inline size_t align4(size_t v) { return (v + 3) & ~(size_t)3; }

extern "C" void kernel_launch(void* const* d_in, const int* in_sizes, int n_in,
                              void* d_out, int out_size, void* d_ws, size_t ws_size,
                              hipStream_t stream) {
    const float* x  = (const float*)d_in[0];
    const int*   ei = (const int*)d_in[1];
    const float* W1 = (const float*)d_in[2];
    const float* b1 = (const float*)d_in[3];
    const float* W2 = (const float*)d_in[4];
    const float* b2 = (const float*)d_in[5];
    float* out = (float*)d_out;

    const int n = in_sizes[0] / 16;
    const int E = in_sizes[1] / 2;
    const int* src = ei;
    const int* dst = ei + E;

    const int gn = (n + B - 1) / B;
    const int ge = (E + B - 1) / B;
    const int n8 = n * 8;

    const int NB   = (n + BDIV - 1) / BDIV;      // dst buckets
    const int NBLK = (E + CHUNK - 1) / CHUNK;    // partition blocks

    // ws layout (int units): hists[NB*NBLK] | totals[NB] | base[NB+1] |
    //   rowinfo[n] | dinv[n] | packed[E] | col[E + 1024*NB]
    // after k_bucket_csr, packed region reused: t[2(n+1)] at +0, x16 at align4(2n+2)
    size_t o_hists  = 0;
    size_t o_totals = align4(o_hists + (size_t)NB * NBLK);
    size_t o_base   = align4(o_totals + NB);
    size_t o_rowinf = align4(o_base + NB + 1);
    size_t o_dinv   = align4(o_rowinf + n);
    size_t o_packed = align4(o_dinv + n);
    size_t o_col    = align4(o_packed + E);
    size_t colsz    = (size_t)E + 1024 * (size_t)NB;
    size_t need_r5  = (o_col + colsz) * 4 + 64;
    size_t reuse_need = align4(2 * (size_t)n + 2) + 4 * ((size_t)n + 1);  // t + x16

    bool r5_ok = (NB <= NB_MAX) && (NBLK <= 512) && (n <= (1 << 20)) &&
                 ((size_t)E + 1024 * (size_t)NB < (RI_MASK + 1)) &&
                 (reuse_need <= (size_t)E) && (ws_size >= need_r5);

    if (r5_ok) {
        int* ws = (int*)d_ws;
        int*      hists  = ws + o_hists;
        int*      totals = ws + o_totals;
        int*      base   = ws + o_base;
        unsigned* rowinf = (unsigned*)(ws + o_rowinf);
        float*    dinv   = (float*)(ws + o_dinv);
        unsigned* packed = (unsigned*)(ws + o_packed);
        int*      col    = ws + o_col;
        float*    t      = (float*)packed;                          // dead after CSR build
        __half2*  x16    = (__half2*)(packed + align4(2 * (size_t)n + 2));

        k_phist<<<NBLK, 256, 0, stream>>>(dst, hists, E, NB, NBLK);
        k_pscan1<<<NB, 512, 0, stream>>>(hists, totals, NBLK);
        k_pscan2<<<1, 1024, 0, stream>>>(totals, base, NB, E);
        k_move<<<NBLK, 256, 0, stream>>>(src, dst, hists, base, packed, E, NB, NBLK);
        k_bucket_csr<<<NB, 256, 0, stream>>>(packed, base, rowinf, dinv, col, n);
        k_prep<<<(n8 + 8 + 255) / 256, 256, 0, stream>>>(x, dinv, x16, t, n8);
        k_l1w<<<(n + 3) / 4, 256, 0, stream>>>(x16, rowinf, col, dinv, W1, b1, W2, t, n);
        k_l2w<<<(8 * n + 255) / 256, 256, 0, stream>>>(rowinf, col, dinv, t, b2, out, n);
        return;
    }

    // ---- fallback (global-atomic hist/fill), padded rowinfo format ----
    const int nb = (n + 1023) / 1024;
    size_t f_cnt    = 0;
    size_t f_rowinf = align4(f_cnt + n);
    size_t f_col    = align4(f_rowinf + n);
    size_t f_dinv   = align4(f_col + E + 8 * (size_t)n);
    size_t f_bsum   = align4(f_dinv + n);
    size_t f_boff   = align4(f_bsum + nb);
    size_t f_rank   = align4(f_boff + nb);
    size_t reuse2   = align4(2 * (size_t)n + 2) + 4 * ((size_t)n + 1);
    size_t rmax = (size_t)E > reuse2 ? (size_t)E : reuse2;
    size_t need_rank = (f_rank + rmax) * 4 + 64;
    if (ws_size >= need_rank && nb <= 1024) {
        int*      ws     = (int*)d_ws;
        int*      cnt    = ws + f_cnt;
        unsigned* rowinf = (unsigned*)(ws + f_rowinf);
        int*      col    = ws + f_col;
        float*    dinv   = (float*)(ws + f_dinv);
        int*      bsum   = ws + f_bsum;
        int*      boff   = ws + f_boff;
        int*      rank   = ws + f_rank;                 // dead after k_fill_rank
        float*    t      = (float*)rank;
        __half2*  x16    = (__half2*)(rank + align4(2 * (size_t)n + 2));

        k_zero<<<gn, B, 0, stream>>>(cnt, n);
        k_hist_rank<<<ge, B, 0, stream>>>(dst, cnt, rank, E);
        k_blocksum<<<nb, 256, 0, stream>>>(cnt, bsum, n);
        k_scan_bsums<<<1, 1024, 0, stream>>>(bsum, boff, nb);
        k_scan_apply<<<nb, 256, 0, stream>>>(cnt, boff, rowinf, dinv, n);
        k_fill_rank<<<ge, B, 0, stream>>>(src, dst, rowinf, rank, col, E);
        k_pad_sent<<<gn, B, 0, stream>>>(rowinf, cnt, col, n);
        k_prep<<<(n8 + 8 + 255) / 256, 256, 0, stream>>>(x, dinv, x16, t, n8);
        k_l1w<<<(n + 3) / 4, 256, 0, stream>>>(x16, rowinf, col, dinv, W1, b1, W2, t, n);
        k_l2w<<<(8 * n + 255) / 256, 256, 0, stream>>>(rowinf, col, dinv, t, b2, out, n);
    }
}